// Round 1
// baseline (143.663 us; speedup 1.0000x reference)
//
#include <hip/hip_runtime.h>

#define B 4
#define N 2048      // N1 == N2
#define F 256
#define O 256
#define LOG2E 1.4426950408889634f
#define NEG_BIG -9000000000000000.0f

typedef _Float16 f16;
typedef f16 f16x4 __attribute__((ext_vector_type(4)));
typedef f16 f16x8 __attribute__((ext_vector_type(8)));
typedef float f32x16 __attribute__((ext_vector_type(16)));

// ws float-index layout
#define WS_V1 0
#define WS_V2 256
#define WS_T1 512              // t1 * LOG2E  per (b,n2)
#define WS_T2 (512 + B*N)     // t2 (unscaled) per (b,n2)
// byte offsets in d_ws
#define WT_OFF (1u << 20)      // wordT swizzled: f16 [B][ft(8)][kc(128)][lane(64)][8] (4 MB)
#define WGT_OFF (8u << 20)     // weights swizzled: f16 [r32(256)][kc(128)][lane(64)][8] (33.5 MB)

__device__ __forceinline__ float alpha_of(float pre2) {
  return __builtin_amdgcn_exp2f(fmaxf(pre2, 0.2f * pre2));
}

// ---------------- kernel 1: v1 = W1 @ w3a, v2 = W2 @ w3b ----------------
__global__ __launch_bounds__(256) void k_v(const float* __restrict__ W1,
                                           const float* __restrict__ W2,
                                           const float* __restrict__ w3,
                                           float* __restrict__ ws) {
  int tid = threadIdx.x;
  int lane = tid & 63;
  int f = blockIdx.x * 4 + (tid >> 6);
  float a = 0.f, b = 0.f;
  #pragma unroll
  for (int k = 0; k < 4; ++k) {
    int o = lane + 64 * k;
    a += W1[f * O + o] * w3[o];
    b += W2[f * O + o] * w3[O + o];
  }
  #pragma unroll
  for (int off = 32; off > 0; off >>= 1) {
    a += __shfl_down(a, off);
    b += __shfl_down(b, off);
  }
  if (lane == 0) {
    ws[WS_V1 + f] = a;
    ws[WS_V2 + f] = b;
  }
}

// ---------------- kernel 2: k_prep = t1/t2 dots + swizzled f16 transpose ----
__global__ __launch_bounds__(256) void k_prep(const float* __restrict__ word,
                                              float* __restrict__ ws,
                                              f16* __restrict__ wordT) {
  __shared__ float v1s[F], v2s[F];
  __shared__ __align__(16) f16 tile[F][40];   // [f][r]
  int t = threadIdx.x;
  int k0 = blockIdx.x * 32;
  int b = blockIdx.y;

  if (t < 64)       ((float4*)v1s)[t]      = ((const float4*)(ws + WS_V1))[t];
  else if (t < 128) ((float4*)v2s)[t - 64] = ((const float4*)(ws + WS_V2))[t - 64];
  __syncthreads();

  int r = t >> 3;        // 0..31
  int cg = t & 7;
  const float* wrow = word + ((size_t)(b * N + k0 + r)) * F;
  float a = 0.f, bb = 0.f;
  #pragma unroll
  for (int i = 0; i < 8; ++i) {
    int c = i * 32 + cg * 4;
    float4 w = *(const float4*)(wrow + c);
    float4 x1 = *(const float4*)(v1s + c);
    float4 x2 = *(const float4*)(v2s + c);
    a  += w.x * x1.x + w.y * x1.y + w.z * x1.z + w.w * x1.w;
    bb += w.x * x2.x + w.y * x2.y + w.z * x2.z + w.w * x2.w;
    tile[c + 0][r] = (f16)w.x;
    tile[c + 1][r] = (f16)w.y;
    tile[c + 2][r] = (f16)w.z;
    tile[c + 3][r] = (f16)w.w;
  }
  #pragma unroll
  for (int off = 4; off > 0; off >>= 1) {
    a  += __shfl_down(a, off);
    bb += __shfl_down(bb, off);
  }
  if (cg == 0) {
    ws[WS_T1 + b * N + k0 + r] = a * LOG2E;
    ws[WS_T2 + b * N + k0 + r] = bb;
  }
  __syncthreads();

  // swizzled writes: [ft][kc][lane][8]; frag: f = ft*32+(l&31), k = kc*16+(l>>5)*8+j
  size_t base = (size_t)b * F * N;
  #pragma unroll
  for (int i = 0; i < 4; ++i) {
    int idx = t + 256 * i;
    int ft = idx >> 7, c = (idx >> 6) & 1, l = idx & 63;
    int f = ft * 32 + (l & 31);
    int rr = c * 16 + ((l >> 5) * 8);
    f16x8 h = *(const f16x8*)&tile[f][rr];
    *(f16x8*)(wordT + base + ((size_t)((ft * 128 + (k0 >> 4) + c) * 64 + l)) * 8) = h;
  }
}

// ---------------- kernel 3: per-row softmax -> final f16 weights ------------
// 1 wave per row, 8 rows (8 waves, 512 thr) per block. Shuffle-only reductions.
// Output pre-swizzled in MFMA A-frag order: [r32][kc][half*32 + r31][8],
// full 128B-line stores via LDS transpose across the block's 8 aligned rows.
__global__ __launch_bounds__(512) void k_weights(const float* __restrict__ adj,
                                                 const float* __restrict__ ws,
                                                 f16* __restrict__ Wt) {
  __shared__ __align__(16) f16 tile[8][2056];   // +8 f16 pad per row
  int t = threadIdx.x;
  int wid = t >> 6, l = t & 63;
  int a = blockIdx.x;                 // 0..1023, rows [8a, 8a+8)
  int row = a * 8 + wid;
  int b = row >> 11;
  const float* arow = adj + (size_t)row * N;
  const float* t1b = ws + WS_T1 + b * N;
  const float* t2b = ws + WS_T2 + b * N;

  // pass 1: deg, dot(adj,t2), 32-bit mask per lane (element j = i*4+c at k=i*256+l*4+c)
  float deg = 0.f, dot = 0.f;
  unsigned mb = 0u;
  #pragma unroll
  for (int i = 0; i < 8; ++i) {
    int k = i * 256 + l * 4;
    float4 av = *(const float4*)(arow + k);
    float4 uv = *(const float4*)(t2b + k);
    deg += av.x + av.y + av.z + av.w;
    dot += av.x * uv.x + av.y * uv.y + av.z * uv.z + av.w * uv.w;
    mb |= (av.x > 0.f ? (1u << (4 * i))     : 0u) |
          (av.y > 0.f ? (1u << (4 * i + 1)) : 0u) |
          (av.z > 0.f ? (1u << (4 * i + 2)) : 0u) |
          (av.w > 0.f ? (1u << (4 * i + 3)) : 0u);
  }
  #pragma unroll
  for (int off = 32; off > 0; off >>= 1) {
    deg += __shfl_xor(deg, off);
    dot += __shfl_xor(dot, off);
  }
  float degc = deg > 0.f ? deg : 1.f;
  float s2p = (dot / degc) * LOG2E;

  // pass 2: alphas + row max
  float al[32];
  float m = NEG_BIG;
  #pragma unroll
  for (int i = 0; i < 8; ++i) {
    int k = i * 256 + l * 4;
    float4 pv = *(const float4*)(t1b + k);
    float p0 = pv.x + s2p, p1 = pv.y + s2p, p2 = pv.z + s2p, p3 = pv.w + s2p;
    al[4 * i + 0] = ((mb >> (4 * i + 0)) & 1u) ? alpha_of(p0) : NEG_BIG;
    al[4 * i + 1] = ((mb >> (4 * i + 1)) & 1u) ? alpha_of(p1) : NEG_BIG;
    al[4 * i + 2] = ((mb >> (4 * i + 2)) & 1u) ? alpha_of(p2) : NEG_BIG;
    al[4 * i + 3] = ((mb >> (4 * i + 3)) & 1u) ? alpha_of(p3) : NEG_BIG;
    m = fmaxf(m, fmaxf(fmaxf(al[4 * i], al[4 * i + 1]), fmaxf(al[4 * i + 2], al[4 * i + 3])));
  }
  #pragma unroll
  for (int off = 32; off > 0; off >>= 1) m = fmaxf(m, __shfl_xor(m, off));

  // pass 3: z-terms kept in place -> weight = zterm * (1/Z)  (no third exp2)
  float negmL = -m * LOG2E;
  float z = 0.f;
  #pragma unroll
  for (int j = 0; j < 32; ++j) {
    float e = __builtin_amdgcn_exp2f(fmaf(al[j], LOG2E, negmL));
    z += e;
    al[j] = e;
  }
  #pragma unroll
  for (int off = 32; off > 0; off >>= 1) z += __shfl_xor(z, off);
  float sc, wn;
  if (deg > 0.f) { sc = 1.0f / z; wn = 0.f; }
  else           { sc = 0.f;      wn = 1.0f / (float)N; }

  // write weights (natural k order) to LDS
  #pragma unroll
  for (int i = 0; i < 8; ++i) {
    f16x4 h;
    #pragma unroll
    for (int c = 0; c < 4; ++c) {
      int j = 4 * i + c;
      float w = ((mb >> j) & 1u) ? al[j] * sc : wn;
      h[c] = (f16)w;
    }
    *(f16x4*)&tile[wid][i * 256 + l * 4] = h;
  }
  __syncthreads();

  // coalesced full-line stores: unit u -> [kc][half*32 + 8*(a&3) + r8][8]
  size_t base16 = (size_t)(a >> 2) * (128 * 64) + 8 * (a & 3);
  #pragma unroll
  for (int s = 0; s < 4; ++s) {
    int u = s * 512 + t;
    int r8 = u & 7, half = (u >> 3) & 1, kc = u >> 4;
    f16x8 v = *(const f16x8*)&tile[r8][kc * 16 + half * 8];
    *(f16x8*)(Wt + (base16 + (size_t)kc * 64 + half * 32 + r8) * 8) = v;
  }
}

// ---------------- kernel 4: pure streaming MFMA GEMM ----------------
// 256 blocks x 512 thr (8 waves), tile 64 rows x 128 cols, no LDS, no barriers.
// A (weights) and B (wordT) both pre-swizzled in frag order: 2 x 16B load + 1 MFMA per chunk.
__global__ __launch_bounds__(512) void k_gemm(const f16* __restrict__ Wt,
                                              const f16* __restrict__ wordT,
                                              float* __restrict__ out) {
  int bid = blockIdx.x;
  int sbid = (bid & 7) * 32 + (bid >> 3);   // XCD-chunked swizzle (256 % 8 == 0)
  int rb2 = sbid >> 1, fh = sbid & 1;
  int t = threadIdx.x;
  int wid = t >> 6, l = t & 63;
  int r32 = rb2 * 2 + (wid >> 2);           // 0..255
  int ftile = fh * 4 + (wid & 3);           // 0..7
  int b = r32 >> 6;

  const f16* ap = Wt + (size_t)r32 * (128 * 512) + l * 8;
  const f16* bp = wordT + (size_t)b * (F * N) + (size_t)ftile * (128 * 512) + l * 8;

  f32x16 acc = {0.f,0.f,0.f,0.f,0.f,0.f,0.f,0.f,0.f,0.f,0.f,0.f,0.f,0.f,0.f,0.f};
  #pragma unroll 8
  for (int c = 0; c < 128; ++c) {
    f16x8 af = *(const f16x8*)(ap + (size_t)c * 512);
    f16x8 bf = *(const f16x8*)(bp + (size_t)c * 512);
    acc = __builtin_amdgcn_mfma_f32_32x32x16_f16(af, bf, acc, 0, 0, 0);
  }

  // C layout: col = lane&31, row = (reg&3)+8*(reg>>2)+4*(lane>>5)
  int row0 = r32 * 32;
  int fcol = ftile * 32 + (l & 31);
  #pragma unroll
  for (int reg = 0; reg < 16; ++reg) {
    int lr = (reg & 3) + 8 * (reg >> 2) + 4 * (l >> 5);
    out[(size_t)(row0 + lr) * F + fcol] = acc[reg];
  }
}

extern "C" void kernel_launch(void* const* d_in, const int* in_sizes, int n_in,
                              void* d_out, int out_size, void* d_ws, size_t ws_size,
                              hipStream_t stream) {
  const float* word = (const float*)d_in[0];
  const float* adj  = (const float*)d_in[1];
  const float* W1   = (const float*)d_in[2];
  const float* W2   = (const float*)d_in[3];
  const float* w3   = (const float*)d_in[4];
  float* out = (float*)d_out;
  float* ws  = (float*)d_ws;
  f16* wordT = (f16*)((char*)d_ws + WT_OFF);
  f16* Wt    = (f16*)((char*)d_ws + WGT_OFF);

  k_v<<<64, 256, 0, stream>>>(W1, W2, w3, ws);
  k_prep<<<dim3(N / 32, B), 256, 0, stream>>>(word, ws, wordT);
  k_weights<<<(B * N) / 8, 512, 0, stream>>>(adj, ws, Wt);
  k_gemm<<<256, 512, 0, stream>>>(Wt, wordT, out);
}

// Round 2
// 131.830 us; speedup vs baseline: 1.0898x; 1.0898x over previous
//
#include <hip/hip_runtime.h>

#define B 4
#define N 2048      // N1 == N2
#define F 256
#define O 256
#define LOG2E 1.4426950408889634f
#define NEG_BIG -9000000000000000.0f

typedef _Float16 f16;
typedef f16 f16x8 __attribute__((ext_vector_type(8)));
typedef float f32x16 __attribute__((ext_vector_type(16)));

// ws float-index layout
#define WS_V1 0
#define WS_V2 256
#define WS_T1 512              // t1 * LOG2E  per (b,n2)
#define WS_T2 (512 + B*N)     // t2 (unscaled) per (b,n2)
// byte offsets in d_ws
#define WT_OFF (1u << 20)      // wordT swizzled: f16 [B][ft(8)][kc(128)][lane(64)][8] (4 MB)

__device__ __forceinline__ float alpha_of(float pre2) {
  return __builtin_amdgcn_exp2f(fmaxf(pre2, 0.2f * pre2));
}

// ---------------- kernel 1: v1 = W1 @ w3a, v2 = W2 @ w3b ----------------
__global__ __launch_bounds__(256) void k_v(const float* __restrict__ W1,
                                           const float* __restrict__ W2,
                                           const float* __restrict__ w3,
                                           float* __restrict__ ws) {
  int tid = threadIdx.x;
  int lane = tid & 63;
  int f = blockIdx.x * 4 + (tid >> 6);
  float a = 0.f, b = 0.f;
  #pragma unroll
  for (int k = 0; k < 4; ++k) {
    int o = lane + 64 * k;
    a += W1[f * O + o] * w3[o];
    b += W2[f * O + o] * w3[O + o];
  }
  #pragma unroll
  for (int off = 32; off > 0; off >>= 1) {
    a += __shfl_down(a, off);
    b += __shfl_down(b, off);
  }
  if (lane == 0) {
    ws[WS_V1 + f] = a;
    ws[WS_V2 + f] = b;
  }
}

// ---------------- kernel 2: k_prep = t1/t2 dots + swizzled f16 transpose ----
__global__ __launch_bounds__(256) void k_prep(const float* __restrict__ word,
                                              float* __restrict__ ws,
                                              f16* __restrict__ wordT) {
  __shared__ float v1s[F], v2s[F];
  __shared__ __align__(16) f16 tile[F][40];   // [f][r]
  int t = threadIdx.x;
  int k0 = blockIdx.x * 32;
  int b = blockIdx.y;

  if (t < 64)       ((float4*)v1s)[t]      = ((const float4*)(ws + WS_V1))[t];
  else if (t < 128) ((float4*)v2s)[t - 64] = ((const float4*)(ws + WS_V2))[t - 64];
  __syncthreads();

  int r = t >> 3;        // 0..31
  int cg = t & 7;
  const float* wrow = word + ((size_t)(b * N + k0 + r)) * F;
  float a = 0.f, bb = 0.f;
  #pragma unroll
  for (int i = 0; i < 8; ++i) {
    int c = i * 32 + cg * 4;
    float4 w = *(const float4*)(wrow + c);
    float4 x1 = *(const float4*)(v1s + c);
    float4 x2 = *(const float4*)(v2s + c);
    a  += w.x * x1.x + w.y * x1.y + w.z * x1.z + w.w * x1.w;
    bb += w.x * x2.x + w.y * x2.y + w.z * x2.z + w.w * x2.w;
    tile[c + 0][r] = (f16)w.x;
    tile[c + 1][r] = (f16)w.y;
    tile[c + 2][r] = (f16)w.z;
    tile[c + 3][r] = (f16)w.w;
  }
  #pragma unroll
  for (int off = 4; off > 0; off >>= 1) {
    a  += __shfl_down(a, off);
    bb += __shfl_down(bb, off);
  }
  if (cg == 0) {
    ws[WS_T1 + b * N + k0 + r] = a * LOG2E;
    ws[WS_T2 + b * N + k0 + r] = bb;
  }
  __syncthreads();

  // swizzled writes: [ft][kc][lane][8]; frag: f = ft*32+(l&31), k = kc*16+(l>>5)*8+j
  size_t base = (size_t)b * F * N;
  #pragma unroll
  for (int i = 0; i < 4; ++i) {
    int idx = t + 256 * i;
    int ft = idx >> 7, c = (idx >> 6) & 1, l = idx & 63;
    int f = ft * 32 + (l & 31);
    int rr = c * 16 + ((l >> 5) * 8);
    f16x8 h = *(const f16x8*)&tile[f][rr];
    *(f16x8*)(wordT + base + ((size_t)((ft * 128 + (k0 >> 4) + c) * 64 + l)) * 8) = h;
  }
}

// ---------------- kernel 3: fused stats + softmax weights + MFMA GEMM --------
// 256 blocks x 512 thr (8 waves), 1 block/CU (LDS-limited). Block owns 32 rows
// x all 256 cols. Phase A: wave w computes rows w*4..w*4+3 (shuffle-only
// reductions) and writes final f16 weights into LDS [32][2048] with XOR swizzle
// byte ^= (row&7)<<4 (conflict-free row-strided ds_read_b128 in Phase B).
// Phase B: wave w = ftile w; 128 x {ds_read A-frag, global B-frag, MFMA}.
__global__ __launch_bounds__(512, 2) void k_sg(const float* __restrict__ adj,
                                               const float* __restrict__ ws,
                                               const f16* __restrict__ wordT,
                                               float* __restrict__ out) {
  extern __shared__ __align__(16) char smem[];        // 147456 B
  float* t1S = (float*)(smem + 131072);               // 8KB
  float* t2S = (float*)(smem + 131072 + 8192);        // 8KB

  const int t = threadIdx.x;
  const int wv = t >> 6, l = t & 63;
  const int row0 = blockIdx.x * 32;                   // global row base
  const int b = row0 >> 11;

  // stage t1/t2 (shared across all 32 rows)
  {
    float4 v0 = *(const float4*)(ws + WS_T1 + b * N + t * 4);
    float4 v1 = *(const float4*)(ws + WS_T2 + b * N + t * 4);
    *(float4*)(t1S + t * 4) = v0;
    *(float4*)(t2S + t * 4) = v1;
  }
  __syncthreads();

  // ---------------- Phase A ----------------
  #pragma unroll 1
  for (int rr = 0; rr < 4; ++rr) {
    const int lrow = wv * 4 + rr;                     // 0..31
    const float* arow = adj + (size_t)(row0 + lrow) * N;

    float deg = 0.f, dot = 0.f;
    unsigned mb = 0u;
    #pragma unroll
    for (int i = 0; i < 4; ++i) {
      int k = i * 512 + l * 8;
      float4 a0 = *(const float4*)(arow + k);
      float4 a1 = *(const float4*)(arow + k + 4);
      float4 u0 = *(const float4*)(t2S + k);
      float4 u1 = *(const float4*)(t2S + k + 4);
      deg += a0.x + a0.y + a0.z + a0.w + a1.x + a1.y + a1.z + a1.w;
      dot += a0.x * u0.x + a0.y * u0.y + a0.z * u0.z + a0.w * u0.w +
             a1.x * u1.x + a1.y * u1.y + a1.z * u1.z + a1.w * u1.w;
      mb |= (a0.x > 0.f ? (1u << (8 * i + 0)) : 0u) |
            (a0.y > 0.f ? (1u << (8 * i + 1)) : 0u) |
            (a0.z > 0.f ? (1u << (8 * i + 2)) : 0u) |
            (a0.w > 0.f ? (1u << (8 * i + 3)) : 0u) |
            (a1.x > 0.f ? (1u << (8 * i + 4)) : 0u) |
            (a1.y > 0.f ? (1u << (8 * i + 5)) : 0u) |
            (a1.z > 0.f ? (1u << (8 * i + 6)) : 0u) |
            (a1.w > 0.f ? (1u << (8 * i + 7)) : 0u);
    }
    #pragma unroll
    for (int off = 32; off > 0; off >>= 1) {
      deg += __shfl_xor(deg, off);
      dot += __shfl_xor(dot, off);
    }
    float degc = deg > 0.f ? deg : 1.f;
    float s2p = (dot / degc) * LOG2E;

    // alphas + row max
    float al[32];
    float m = NEG_BIG;
    #pragma unroll
    for (int i = 0; i < 4; ++i) {
      int k = i * 512 + l * 8;
      float4 p0 = *(const float4*)(t1S + k);
      float4 p1 = *(const float4*)(t1S + k + 4);
      const float pv[8] = {p0.x, p0.y, p0.z, p0.w, p1.x, p1.y, p1.z, p1.w};
      #pragma unroll
      for (int c = 0; c < 8; ++c) {
        int j = 8 * i + c;
        al[j] = ((mb >> j) & 1u) ? alpha_of(pv[c] + s2p) : NEG_BIG;
        m = fmaxf(m, al[j]);
      }
    }
    #pragma unroll
    for (int off = 32; off > 0; off >>= 1) m = fmaxf(m, __shfl_xor(m, off));

    // z-terms in place -> weight = zterm * (1/Z)
    float negmL = -m * LOG2E;
    float z = 0.f;
    #pragma unroll
    for (int j = 0; j < 32; ++j) {
      float e = __builtin_amdgcn_exp2f(fmaf(al[j], LOG2E, negmL));
      z += e;
      al[j] = e;
    }
    #pragma unroll
    for (int off = 32; off > 0; off >>= 1) z += __shfl_xor(z, off);
    float sc, wn;
    if (deg > 0.f) { sc = 1.0f / z; wn = 0.f; }
    else           { sc = 0.f;      wn = 1.0f / (float)N; }

    // write f16 weights to LDS, natural [row][k], XOR-swizzled
    #pragma unroll
    for (int i = 0; i < 4; ++i) {
      f16x8 h;
      #pragma unroll
      for (int c = 0; c < 8; ++c) {
        int j = 8 * i + c;
        float w = ((mb >> j) & 1u) ? al[j] * sc : wn;
        h[c] = (f16)w;
      }
      unsigned byteoff = (unsigned)(lrow * 4096 + i * 1024 + l * 16) ^ ((unsigned)(lrow & 7) << 4);
      *(f16x8*)(smem + byteoff) = h;
    }
  }
  __syncthreads();

  // ---------------- Phase B ----------------
  const int ftile = wv;                               // 0..7
  const int rowl = l & 31;
  const unsigned rbase = (unsigned)(rowl * 4096 + (l >> 5) * 16);
  const unsigned rx = (unsigned)(rowl & 7) << 4;
  const f16* bp = wordT + (size_t)b * (F * N) + (size_t)ftile * (128 * 512) + (size_t)l * 8;

  f32x16 acc = {0.f,0.f,0.f,0.f,0.f,0.f,0.f,0.f,0.f,0.f,0.f,0.f,0.f,0.f,0.f,0.f};
  #pragma unroll 8
  for (int kc = 0; kc < 128; ++kc) {
    f16x8 af = *(const f16x8*)(smem + ((rbase + kc * 32) ^ rx));
    f16x8 bf = *(const f16x8*)(bp + (size_t)kc * 512);
    acc = __builtin_amdgcn_mfma_f32_32x32x16_f16(af, bf, acc, 0, 0, 0);
  }

  // C layout: col = lane&31, row = (reg&3)+8*(reg>>2)+4*(lane>>5)
  const int fcol = ftile * 32 + (l & 31);
  #pragma unroll
  for (int reg = 0; reg < 16; ++reg) {
    int lr = (reg & 3) + 8 * (reg >> 2) + 4 * (l >> 5);
    out[(size_t)(row0 + lr) * F + fcol] = acc[reg];
  }
}

extern "C" void kernel_launch(void* const* d_in, const int* in_sizes, int n_in,
                              void* d_out, int out_size, void* d_ws, size_t ws_size,
                              hipStream_t stream) {
  const float* word = (const float*)d_in[0];
  const float* adj  = (const float*)d_in[1];
  const float* W1   = (const float*)d_in[2];
  const float* W2   = (const float*)d_in[3];
  const float* w3   = (const float*)d_in[4];
  float* out = (float*)d_out;
  float* ws  = (float*)d_ws;
  f16* wordT = (f16*)((char*)d_ws + WT_OFF);

  static bool s_attr = false;
  if (!s_attr) {
    hipFuncSetAttribute((const void*)k_sg, hipFuncAttributeMaxDynamicSharedMemorySize, 147456);
    s_attr = true;
  }

  k_v<<<64, 256, 0, stream>>>(W1, W2, w3, ws);
  k_prep<<<dim3(N / 32, B), 256, 0, stream>>>(word, ws, wordT);
  k_sg<<<(B * N) / 32, 512, 147456, stream>>>(adj, ws, wordT, out);
}